// Round 10
// baseline (2426.959 us; speedup 1.0000x reference)
//
#include <hip/hip_runtime.h>
#include <cmath>

#define MSG 128
#define TILE 32      // edges per LDS tile (16 KB staged)
#define TPB 256      // 4 waves; each wave owns 32 hidden units
#define NB_MAX 768   // 3 blocks/CU

typedef __attribute__((ext_vector_type(8))) __bf16 bf16x8;
typedef __attribute__((ext_vector_type(4))) float f32x4;

__device__ __forceinline__ unsigned short f2bf(float f) {
  union { float f; unsigned u; } v; v.f = f;
  unsigned r = v.u + 0x7FFFu + ((v.u >> 16) & 1u);  // round-to-nearest-even
  return (unsigned short)(r >> 16);
}

// ---- Kernel 1: convert + transpose both hidden-layer weight matrices to bf16.
__global__ void prep_weights_kernel(const float* __restrict__ Ww1,
                                    const float* __restrict__ Wa1,
                                    unsigned short* __restrict__ WtW,
                                    unsigned short* __restrict__ WtA) {
  int idx = blockIdx.x * blockDim.x + threadIdx.x;
  if (idx < MSG * MSG) {
    int k = idx >> 7;
    int n = idx & 127;
    WtW[n * MSG + k] = f2bf(Ww1[idx]);
    WtA[n * MSG + k] = f2bf(Wa1[idx]);
  }
}

__device__ __forceinline__ void gload_lds16(const float* g, float* l) {
  __builtin_amdgcn_global_load_lds(
      (const __attribute__((address_space(1))) void*)g,
      (__attribute__((address_space(3))) void*)l, 16, 0, 0);
}

// ---- Kernel 2: persistent edge pass with a DEFERRED epilogue (2-stage wave
// pipeline) and ONE barrier per tile. (R9 schedule; R10 = two bugfixes only:
// clds staged by all 512 entries from 256 threads, and pacc stored in-order.)
// Iteration i:
//   A sd(t+1)  B stage(t+2, 3 bufs)  C epilogue(t-1)->plds  [barrier]
//   E MFMA(t)->pacc  ||  F finalize(t-1) (plds + x regs + atomics)
//   G vmcnt(8) (drains sd(t+1); staging stays in flight); issue x(t+1) [barrier]
// Queue invariant (steady state at G): outstanding = {k-1 atomics 4, k-1 x 6,
// k sd 2, k stage 4, k atomics 4}; vmcnt(8) leaves {k stage, k atomics}.
// Stage(k) is consumed at iter k+2's E, one closing barrier after its drain
// at iter k+1's G -> buf residency is guaranteed without draining mid-window.
__global__ __launch_bounds__(TPB, 3)
void edge_mlp_pipe_kernel(const float* __restrict__ m_ij,
                          const unsigned short* __restrict__ WtW,
                          const unsigned short* __restrict__ WtA,
                          const float* __restrict__ bw1, const float* __restrict__ Ww2,
                          const float* __restrict__ bw2,
                          const float* __restrict__ ba1, const float* __restrict__ Wa2,
                          const float* __restrict__ ba2,
                          const int* __restrict__ src,
                          const int* __restrict__ dst,
                          const float* __restrict__ x,
                          float* __restrict__ num4, int E, int ntiles) {
  __shared__ __align__(16) float buf[3][TILE * MSG];  // 3 x 16KB, swizzled rows
  __shared__ float plds[2][4][TILE];                  // [mlp][wave][edge] 1KB
  __shared__ float clds[2][2][MSG];                   // [mat][b1|w2][unit] 2KB

  const int tid = threadIdx.x;
  const int w = tid >> 6;       // 0..3
  const int lane = tid & 63;
  const int quad = lane >> 4;
  const int l16 = lane & 15;
  const int G = (int)gridDim.x;

  // Stage MLP constants into LDS: 512 entries from 256 threads (2 each).
  // (R9 bug: `if (tid < 512)` left clds[1][..] -- attention constants --
  // uninitialized, since tid>>8==0 for all 256 threads.)
  for (int e = tid; e < 512; e += TPB) {
    const int mat = e >> 8, c = (e >> 7) & 1, u = e & 127;
    const float* s = (mat == 0) ? (c == 0 ? bw1 : Ww2) : (c == 0 ? ba1 : Wa2);
    clds[mat][c][u] = s[u];
  }

  // Persistent weights: wave w owns hidden units [32w, 32w+32).
  bf16x8 wf[2][2][4];  // [nt][mat W/A][kt]
  #pragma unroll
  for (int nt = 0; nt < 2; ++nt) {
    const size_t ro = (size_t)(w * 32 + nt * 16 + l16) * MSG + quad * 8;
    #pragma unroll
    for (int kt = 0; kt < 4; ++kt) {
      wf[nt][0][kt] = *(const bf16x8*)(WtW + ro + kt * 32);
      wf[nt][1][kt] = *(const bf16x8*)(WtA + ro + kt * 32);
    }
  }
  const float bw2s = bw2[0], ba2s = ba2[0];

  // Stage one 32x128 fp32 tile (16KB). LDS dest linear; XOR swizzle
  // (byte ^= (row&7)<<4) applied to the GLOBAL source (T21).
  auto stage = [&](int tile, float* base) {
    #pragma unroll
    for (int i = 0; i < 4; ++i) {
      const int chunk = i * TPB + tid;        // 0..1023
      const int db = chunk * 16;              // [0, 16384)
      const int row = db >> 9;                // 512B rows
      const int col = db & 511;
      const int scol = col ^ ((row & 7) << 4);
      int grow = tile * TILE + row;
      if (grow >= E) grow = E - 1;
      gload_lds16(m_ij + (size_t)grow * MSG + (scol >> 2), base + (db >> 2));
    }
  };

  // Finalize ownership: lane handles edge fid (x8 lane redundancy on loads,
  // same cache lines); atomics predicated on quad==0 && l16<8.
  const int fid = w * 8 + (lane & 7);

  // Two finalize generations (gen[p] consumed & rewritten each iter).
  int fsN[2] = {0, 0};
  float fm[2] = {0.f, 0.f};
  float fX[2][6];
  #pragma unroll
  for (int k = 0; k < 6; ++k) { fX[0][k] = 0.f; fX[1][k] = 0.f; }

  // Deferred accumulators: pacc[et*4 + nt*2 + mat] (stored in-order at E).
  f32x4 pacc[8];
  #pragma unroll
  for (int k = 0; k < 8; ++k) pacc[k] = {0.f, 0.f, 0.f, 0.f};

  // ---- Prologue: stage t0,t1; prefetch finalize data of t0 into gen[1].
  const int t0 = blockIdx.x;
  {
    int ge = t0 * TILE + fid;
    bool v = (ge < E);
    int gec = v ? ge : 0;
    int sN = src[gec], dN = dst[gec];
    stage(t0, &buf[0][0]);
    { int t1 = t0 + G; if (t1 >= ntiles) t1 = ntiles - 1; stage(t1, &buf[1][0]); }
    fsN[1] = sN; fm[1] = v ? 1.f : 0.f;
    fX[1][0] = x[3 * sN]; fX[1][1] = x[3 * sN + 1]; fX[1][2] = x[3 * sN + 2];
    fX[1][3] = x[3 * dN]; fX[1][4] = x[3 * dN + 1]; fX[1][5] = x[3 * dN + 2];
    __syncthreads();   // full drain once; covers clds + buf[0..1] + x
  }

  int p = 0;   // iter0: epilogue/finalize are of a dummy "t0-1" (pacc=0, fm[0]=0)
  int ci = 0;

  for (int tt = t0; tt < ntiles; tt += G) {
    // A: sd(t+1) -- issued before staging so its consumption at G drains
    //    nothing younger than it (staging stays in flight).
    int tn = tt + G;
    const bool tnok = tn < ntiles;
    const int tnc = tnok ? tn : ntiles - 1;
    const int geN = tnc * TILE + fid;
    const bool vN = tnok && (geN < E);
    const int geNc = vN ? geN : 0;
    const int sN2 = src[geNc];
    const int dN2 = dst[geNc];

    // B: fire-and-forget staging of t+2 into the third buffer.
    { int ts = tt + 2 * G; if (ts >= ntiles) ts = ntiles - 1;
      int sb = ci + 2; if (sb >= 3) sb -= 3;
      stage(ts, &buf[sb][0]); }

    // C: deferred epilogue of tile t-1 (pure VALU/trans; overlaps delivery).
    #pragma unroll
    for (int et = 0; et < 2; ++et) {
      float pW = 0.f, pA = 0.f;
      #pragma unroll
      for (int nt = 0; nt < 2; ++nt) {
        const int co = w * 32 + nt * 16 + quad * 4;
        const f32x4 b1w = *(const f32x4*)&clds[0][0][co];
        const f32x4 w2w = *(const f32x4*)&clds[0][1][co];
        const f32x4 b1a = *(const f32x4*)&clds[1][0][co];
        const f32x4 w2a = *(const f32x4*)&clds[1][1][co];
        #pragma unroll
        for (int r = 0; r < 4; ++r) {
          const float hw = pacc[et * 4 + nt * 2 + 0][r] + b1w[r];
          const float ha = pacc[et * 4 + nt * 2 + 1][r] + b1a[r];
          // silu via rcp: saturation-safe (exp(-h)->inf => rcp->0 => silu->0).
          pW += (hw * w2w[r]) * __builtin_amdgcn_rcpf(1.f + __expf(-hw));
          pA += (ha * w2a[r]) * __builtin_amdgcn_rcpf(1.f + __expf(-ha));
        }
      }
      pW += __shfl_xor(pW, 16, 64); pW += __shfl_xor(pW, 32, 64);
      pA += __shfl_xor(pA, 16, 64); pA += __shfl_xor(pA, 32, 64);
      if (quad == 0) {
        plds[0][w][et * 16 + l16] = pW;
        plds[1][w][et * 16 + l16] = pA;
      }
    }

    // Barrier: plds(t-1) visible; buf(t) known-resident (drained last iter).
    asm volatile("s_waitcnt lgkmcnt(0)" ::: "memory");
    __builtin_amdgcn_s_barrier();

    // E: MFMA(t) from swizzled LDS -> pacc (consumed next iter).
    {
      const float* bufc = &buf[ci][0];
      #pragma unroll
      for (int et = 0; et < 2; ++et) {
        const int row = et * 16 + l16;
        const int rbase = row * MSG;
        const int xorf = (row & 7) << 2;    // float-index xor (= byte<<4)
        bf16x8 bfv[4];
        #pragma unroll
        for (int kt = 0; kt < 4; ++kt) {
          const int c0 = quad * 8 + kt * 32;
          const f32x4 v0 = *(const f32x4*)(bufc + rbase + (c0 ^ xorf));
          const f32x4 v1 = *(const f32x4*)(bufc + rbase + ((c0 + 4) ^ xorf));
          bf16x8 f;
          f[0] = (__bf16)v0.x; f[1] = (__bf16)v0.y;
          f[2] = (__bf16)v0.z; f[3] = (__bf16)v0.w;
          f[4] = (__bf16)v1.x; f[5] = (__bf16)v1.y;
          f[6] = (__bf16)v1.z; f[7] = (__bf16)v1.w;
          bfv[kt] = f;
        }
        f32x4 a0 = {0.f,0.f,0.f,0.f}, a1 = {0.f,0.f,0.f,0.f};
        f32x4 a2 = {0.f,0.f,0.f,0.f}, a3 = {0.f,0.f,0.f,0.f};
        #pragma unroll
        for (int kt = 0; kt < 4; ++kt) {
          a0 = __builtin_amdgcn_mfma_f32_16x16x32_bf16(wf[0][0][kt], bfv[kt], a0, 0, 0, 0);
          a1 = __builtin_amdgcn_mfma_f32_16x16x32_bf16(wf[0][1][kt], bfv[kt], a1, 0, 0, 0);
          a2 = __builtin_amdgcn_mfma_f32_16x16x32_bf16(wf[1][0][kt], bfv[kt], a2, 0, 0, 0);
          a3 = __builtin_amdgcn_mfma_f32_16x16x32_bf16(wf[1][1][kt], bfv[kt], a3, 0, 0, 0);
        }
        // In-order packing matching the epilogue's pacc[et*4 + nt*2 + mat]:
        // a0=(nt0,W)->+0, a1=(nt0,A)->+1, a2=(nt1,W)->+2, a3=(nt1,A)->+3.
        pacc[et * 4 + 0] = a0;
        pacc[et * 4 + 1] = a1;
        pacc[et * 4 + 2] = a2;
        pacc[et * 4 + 3] = a3;
      }
    }

    // F: finalize(t-1) -- independent of E, interleaves with MFMA.
    {
      float sW = plds[0][0][fid] + plds[0][1][fid] + plds[0][2][fid] + plds[0][3][fid];
      float sA = plds[1][0][fid] + plds[1][1][fid] + plds[1][2][fid] + plds[1][3][fid];
      const float a = __expf(sA + ba2s);
      const float t = (sW + bw2s) * a;
      const float dx = fX[p][3] - fX[p][0];
      const float dy = fX[p][4] - fX[p][1];
      const float dz = fX[p][5] - fX[p][2];
      const float nrm = sqrtf(dx * dx + dy * dy + dz * dz);
      const float inv = t * __builtin_amdgcn_rcpf(fmaxf(nrm, 1e-12f));
      const float m = fm[p];
      if (quad == 0 && l16 < 8) {
        float* bp = num4 + (size_t)4 * fsN[p];
        atomicAdd(bp + 0, dx * inv * m);
        atomicAdd(bp + 1, dy * inv * m);
        atomicAdd(bp + 2, dz * inv * m);
        atomicAdd(bp + 3, a * m);
      }
    }

    // G: consume sd(t+1); staging of t+1 (issued last iter) is already
    // drained by last iter's G; this vmcnt leaves current staging in flight.
    asm volatile("s_waitcnt vmcnt(8)" ::: "memory");
    fsN[p] = sN2; fm[p] = vN ? 1.f : 0.f;
    fX[p][0] = x[3 * sN2]; fX[p][1] = x[3 * sN2 + 1]; fX[p][2] = x[3 * sN2 + 2];
    fX[p][3] = x[3 * dN2]; fX[p][4] = x[3 * dN2 + 1]; fX[p][5] = x[3 * dN2 + 2];

    // Closing barrier (protects plds rewrite and buf rotation next iter).
    asm volatile("s_waitcnt lgkmcnt(0)" ::: "memory");
    __builtin_amdgcn_s_barrier();

    p ^= 1;
    ci = (ci == 2) ? 0 : ci + 1;
  }

  // ---- Trailing: epilogue + finalize of the LAST tile.
  #pragma unroll
  for (int et = 0; et < 2; ++et) {
    float pW = 0.f, pA = 0.f;
    #pragma unroll
    for (int nt = 0; nt < 2; ++nt) {
      const int co = w * 32 + nt * 16 + quad * 4;
      const f32x4 b1w = *(const f32x4*)&clds[0][0][co];
      const f32x4 w2w = *(const f32x4*)&clds[0][1][co];
      const f32x4 b1a = *(const f32x4*)&clds[1][0][co];
      const f32x4 w2a = *(const f32x4*)&clds[1][1][co];
      #pragma unroll
      for (int r = 0; r < 4; ++r) {
        const float hw = pacc[et * 4 + nt * 2 + 0][r] + b1w[r];
        const float ha = pacc[et * 4 + nt * 2 + 1][r] + b1a[r];
        pW += (hw * w2w[r]) * __builtin_amdgcn_rcpf(1.f + __expf(-hw));
        pA += (ha * w2a[r]) * __builtin_amdgcn_rcpf(1.f + __expf(-ha));
      }
    }
    pW += __shfl_xor(pW, 16, 64); pW += __shfl_xor(pW, 32, 64);
    pA += __shfl_xor(pA, 16, 64); pA += __shfl_xor(pA, 32, 64);
    if (quad == 0) {
      plds[0][w][et * 16 + l16] = pW;
      plds[1][w][et * 16 + l16] = pA;
    }
  }
  asm volatile("s_waitcnt lgkmcnt(0)" ::: "memory");
  __builtin_amdgcn_s_barrier();
  {
    float sW = plds[0][0][fid] + plds[0][1][fid] + plds[0][2][fid] + plds[0][3][fid];
    float sA = plds[1][0][fid] + plds[1][1][fid] + plds[1][2][fid] + plds[1][3][fid];
    const float a = __expf(sA + ba2s);
    const float t = (sW + bw2s) * a;
    const float dx = fX[p][3] - fX[p][0];
    const float dy = fX[p][4] - fX[p][1];
    const float dz = fX[p][5] - fX[p][2];
    const float nrm = sqrtf(dx * dx + dy * dy + dz * dz);
    const float inv = t * __builtin_amdgcn_rcpf(fmaxf(nrm, 1e-12f));
    const float m = fm[p];
    if (quad == 0 && l16 < 8) {
      float* bp = num4 + (size_t)4 * fsN[p];
      atomicAdd(bp + 0, dx * inv * m);
      atomicAdd(bp + 1, dy * inv * m);
      atomicAdd(bp + 2, dz * inv * m);
      atomicAdd(bp + 3, a * m);
    }
  }
}

// ---- Kernel 3: per-node finalize. out = x + num.xyz / num.w (0 if no edges).
__global__ void finalize_kernel(const float* __restrict__ x,
                                const f32x4* __restrict__ num4,
                                float* __restrict__ out, int N) {
  int n = blockIdx.x * blockDim.x + threadIdx.x;
  if (n >= N) return;
  const f32x4 v = num4[n];
  const float inv = (v[3] != 0.f) ? __builtin_amdgcn_rcpf(v[3]) : 0.f;
  out[3 * n + 0] = x[3 * n + 0] + v[0] * inv;
  out[3 * n + 1] = x[3 * n + 1] + v[1] * inv;
  out[3 * n + 2] = x[3 * n + 2] + v[2] * inv;
}

extern "C" void kernel_launch(void* const* d_in, const int* in_sizes, int n_in,
                              void* d_out, int out_size, void* d_ws, size_t ws_size,
                              hipStream_t stream) {
  const float* x    = (const float*)d_in[0];
  const float* m_ij = (const float*)d_in[1];
  const int*   edges = (const int*)d_in[2];
  const float* Ww1 = (const float*)d_in[3];
  const float* bw1 = (const float*)d_in[4];
  const float* Ww2 = (const float*)d_in[5];
  const float* bw2 = (const float*)d_in[6];
  const float* Wa1 = (const float*)d_in[7];
  const float* ba1 = (const float*)d_in[8];
  const float* Wa2 = (const float*)d_in[9];
  const float* ba2 = (const float*)d_in[10];

  const int N = in_sizes[0] / 3;
  const int E = in_sizes[1] / MSG;
  const int* src = edges;        // edges[0] = receiver
  const int* dst = edges + E;    // edges[1] = neighbor

  // Workspace layout (~1.7 MB)
  char* p = (char*)d_ws;
  unsigned short* WtW = (unsigned short*)p; p += (size_t)MSG * MSG * 2;
  unsigned short* WtA = (unsigned short*)p; p += (size_t)MSG * MSG * 2;
  float* num4 = (float*)p; p += (size_t)N * 4 * 4;

  float* out = (float*)d_out;

  const int ntiles = (E + TILE - 1) / TILE;
  const int nb = ntiles < NB_MAX ? ntiles : NB_MAX;

  hipMemsetAsync(num4, 0, (size_t)N * 4 * 4, stream);
  prep_weights_kernel<<<(MSG * MSG + 255) / 256, 256, 0, stream>>>(Ww1, Wa1, WtW, WtA);
  edge_mlp_pipe_kernel<<<nb, TPB, 0, stream>>>(
      m_ij, WtW, WtA, bw1, Ww2, bw2, ba1, Wa2, ba2, src, dst, x, num4, E, ntiles);
  finalize_kernel<<<(N + 255) / 256, 256, 0, stream>>>(x, (const f32x4*)num4, out, N);
}

// Round 11
// 1225.624 us; speedup vs baseline: 1.9802x; 1.9802x over previous
//
#include <hip/hip_runtime.h>
#include <cmath>

#define MSG 128
#define TILE 32      // edges per LDS tile (16 KB staged)
#define TPB 256      // 4 waves; each wave owns 32 hidden units
#define NB_MAX 768   // 3 blocks/CU

typedef __attribute__((ext_vector_type(8))) __bf16 bf16x8;
typedef __attribute__((ext_vector_type(4))) float f32x4;

__device__ __forceinline__ unsigned short f2bf(float f) {
  union { float f; unsigned u; } v; v.f = f;
  unsigned r = v.u + 0x7FFFu + ((v.u >> 16) & 1u);  // round-to-nearest-even
  return (unsigned short)(r >> 16);
}

// ---- Kernel 1: convert + transpose both hidden-layer weight matrices to bf16.
__global__ void prep_weights_kernel(const float* __restrict__ Ww1,
                                    const float* __restrict__ Wa1,
                                    unsigned short* __restrict__ WtW,
                                    unsigned short* __restrict__ WtA) {
  int idx = blockIdx.x * blockDim.x + threadIdx.x;
  if (idx < MSG * MSG) {
    int k = idx >> 7;
    int n = idx & 127;
    WtW[n * MSG + k] = f2bf(Ww1[idx]);
    WtA[n * MSG + k] = f2bf(Wa1[idx]);
  }
}

__device__ __forceinline__ void gload_lds16(const float* g, float* l) {
  __builtin_amdgcn_global_load_lds(
      (const __attribute__((address_space(1))) void*)g,
      (__attribute__((address_space(3))) void*)l, 16, 0, 0);
}

// ---- Kernel 2: deferred-epilogue pipeline, 2x-unrolled (R10 schedule with
// the rule-#20 scratch bug fixed: NO runtime-indexed private arrays).
// Per half (tile T): A sd(T+G) | B stage(T+2G) | C epilogue(T-1)->plds |
// [barrier] | E MFMA(T)->pacc | F finalize(T-1) (named x/s/m set + plds +
// atomics) | G vmcnt(8), x(T+G) gathers into this half's named set | [barrier]
// Two named register sets: set A owned by half-1, set B by half-2; each is
// consumed at F and rewritten at G of its own half -> load->use distance is
// one full unrolled iteration, no copies, no scratch.
// Pipeline flush: halves padded with masked dummies (clamped real tiles,
// m=0 -> finite values * 0), so no trailing code.
// VMEM queue/half: sd2+stg4+at4+x6=16; vmcnt(8)@G leaves {stg4,at4}; staging
// is drained by the compiler's x-wait at F one half before its consumption.
__global__ __launch_bounds__(TPB, 3)
void edge_mlp_pipe_kernel(const float* __restrict__ m_ij,
                          const unsigned short* __restrict__ WtW,
                          const unsigned short* __restrict__ WtA,
                          const float* __restrict__ bw1, const float* __restrict__ Ww2,
                          const float* __restrict__ bw2,
                          const float* __restrict__ ba1, const float* __restrict__ Wa2,
                          const float* __restrict__ ba2,
                          const int* __restrict__ src,
                          const int* __restrict__ dst,
                          const float* __restrict__ x,
                          float* __restrict__ num4, int E, int ntiles) {
  __shared__ __align__(16) float buf[3][TILE * MSG];  // 3 x 16KB, swizzled rows
  __shared__ float plds[2][4][TILE];                  // [mlp][wave][edge] 1KB
  __shared__ float clds[2][2][MSG];                   // [mat][b1|w2][unit] 2KB

  const int tid = threadIdx.x;
  const int w = tid >> 6;       // 0..3
  const int lane = tid & 63;
  const int quad = lane >> 4;
  const int l16 = lane & 15;
  const int G = (int)gridDim.x;

  // Stage MLP constants into LDS: 512 entries from 256 threads (2 each).
  for (int e = tid; e < 512; e += TPB) {
    const int mat = e >> 8, c = (e >> 7) & 1, u = e & 127;
    const float* s = (mat == 0) ? (c == 0 ? bw1 : Ww2) : (c == 0 ? ba1 : Wa2);
    clds[mat][c][u] = s[u];
  }

  // Persistent weights: wave w owns hidden units [32w, 32w+32).
  bf16x8 wf[2][2][4];  // [nt][mat W/A][kt]
  #pragma unroll
  for (int nt = 0; nt < 2; ++nt) {
    const size_t ro = (size_t)(w * 32 + nt * 16 + l16) * MSG + quad * 8;
    #pragma unroll
    for (int kt = 0; kt < 4; ++kt) {
      wf[nt][0][kt] = *(const bf16x8*)(WtW + ro + kt * 32);
      wf[nt][1][kt] = *(const bf16x8*)(WtA + ro + kt * 32);
    }
  }
  const float bw2s = bw2[0], ba2s = ba2[0];

  // Stage one 32x128 fp32 tile (16KB). LDS dest linear; XOR swizzle
  // (byte ^= (row&7)<<4) applied to the GLOBAL source (T21).
  auto stage = [&](int tile, float* base) {
    #pragma unroll
    for (int i = 0; i < 4; ++i) {
      const int chunk = i * TPB + tid;        // 0..1023
      const int db = chunk * 16;              // [0, 16384)
      const int row = db >> 9;                // 512B rows
      const int col = db & 511;
      const int scol = col ^ ((row & 7) << 4);
      int grow = tile * TILE + row;
      if (grow >= E) grow = E - 1;
      gload_lds16(m_ij + (size_t)grow * MSG + (scol >> 2), base + (db >> 2));
    }
  };

  // Finalize ownership: lane handles edge fid (x8 lane redundancy on loads);
  // atomics predicated on quad==0 && l16<8 (8 lanes per wave, every wave).
  const int fid = w * 8 + (lane & 7);

  // Named pipeline sets (scalars only -- rule #20).
  int   sAf = 0;  float mAf = 0.f;
  float xA0 = 0.f, xA1 = 0.f, xA2 = 0.f, xA3 = 0.f, xA4 = 0.f, xA5 = 0.f;
  int   sBf;      float mBf;
  float xB0, xB1, xB2, xB3, xB4, xB5;

  // Deferred accumulators: pacc[et*4 + nt*2 + mat], static indices only.
  f32x4 pacc[8];
  #pragma unroll
  for (int k = 0; k < 8; ++k) pacc[k] = {0.f, 0.f, 0.f, 0.f};

  // ---- Prologue: stage t0,t1; t0's finalize data -> set B (consumed at
  // F(half-2, iter 0), which finalizes t0). Set A = masked dummy.
  const int t0 = blockIdx.x;
  {
    stage(t0, &buf[0][0]);
    int t1 = t0 + G; if (t1 >= ntiles) t1 = ntiles - 1;
    stage(t1, &buf[1][0]);
    int ge = t0 * TILE + fid;
    bool v = ge < E;
    int gec = v ? ge : E - 1;
    int sN = src[gec], dN = dst[gec];
    sBf = sN; mBf = v ? 1.f : 0.f;
    xB0 = x[3 * sN]; xB1 = x[3 * sN + 1]; xB2 = x[3 * sN + 2];
    xB3 = x[3 * dN]; xB4 = x[3 * dN + 1]; xB5 = x[3 * dN + 2];
    sAf = sN;   // valid node; set-A adds are m=0 masked
    __syncthreads();   // one-time full drain (clds, buf0/1, x)
  }

  const int nsteps = (ntiles - t0 + G - 1) / G;   // >= 1 (grid <= ntiles)
  const int niter = (nsteps + 2) >> 1;            // halves >= nsteps + 1

  // One half of the unrolled pipeline. (s_f,m_f,x0..x5) is this half's named
  // set: consumed at F (tile T-G's finalize), rewritten at G (tile T+G data).
  auto half = [&](int tth, int bidx, int sbidx,
                  int& s_f, float& m_f,
                  float& x0, float& x1, float& x2,
                  float& x3, float& x4, float& x5) {
    // A: sd of the NEXT half's tile (T+G).
    const int tnh = tth + G;
    const int tcn = (tnh < ntiles) ? tnh : ntiles - 1;
    const int geN = tcn * TILE + fid;
    const bool vN = (tnh < ntiles) && (geN < E);
    const int gecl = (geN < E) ? geN : E - 1;
    const int sNn = src[gecl];
    const int dNn = dst[gecl];

    // B: fire-and-forget staging of T+2G (clamped) into buf[sbidx].
    { int ts = tth + 2 * G; if (ts >= ntiles) ts = ntiles - 1;
      stage(ts, &buf[sbidx][0]); }

    // C: deferred epilogue of the PREVIOUS half's tile (pacc -> plds).
    #pragma unroll
    for (int et = 0; et < 2; ++et) {
      float pW = 0.f, pA = 0.f;
      #pragma unroll
      for (int nt = 0; nt < 2; ++nt) {
        const int co = w * 32 + nt * 16 + quad * 4;
        const f32x4 b1w = *(const f32x4*)&clds[0][0][co];
        const f32x4 w2w = *(const f32x4*)&clds[0][1][co];
        const f32x4 b1a = *(const f32x4*)&clds[1][0][co];
        const f32x4 w2a = *(const f32x4*)&clds[1][1][co];
        #pragma unroll
        for (int r = 0; r < 4; ++r) {
          const float hw = pacc[et * 4 + nt * 2 + 0][r] + b1w[r];
          const float ha = pacc[et * 4 + nt * 2 + 1][r] + b1a[r];
          // silu via rcp: saturation-safe (exp(-h)->inf => rcp->0).
          pW += (hw * w2w[r]) * __builtin_amdgcn_rcpf(1.f + __expf(-hw));
          pA += (ha * w2a[r]) * __builtin_amdgcn_rcpf(1.f + __expf(-ha));
        }
      }
      pW += __shfl_xor(pW, 16, 64); pW += __shfl_xor(pW, 32, 64);
      pA += __shfl_xor(pA, 16, 64); pA += __shfl_xor(pA, 32, 64);
      if (quad == 0) {
        plds[0][w][et * 16 + l16] = pW;
        plds[1][w][et * 16 + l16] = pA;
      }
    }

    asm volatile("s_waitcnt lgkmcnt(0)" ::: "memory");
    __builtin_amdgcn_s_barrier();

    // E: MFMA(T) from swizzled LDS -> pacc (consumed next half's C).
    {
      const float* bufc = &buf[bidx][0];
      #pragma unroll
      for (int et = 0; et < 2; ++et) {
        const int row = et * 16 + l16;
        const int rbase = row * MSG;
        const int xorf = (row & 7) << 2;
        bf16x8 bfv[4];
        #pragma unroll
        for (int kt = 0; kt < 4; ++kt) {
          const int c0 = quad * 8 + kt * 32;
          const f32x4 v0 = *(const f32x4*)(bufc + rbase + (c0 ^ xorf));
          const f32x4 v1 = *(const f32x4*)(bufc + rbase + ((c0 + 4) ^ xorf));
          bf16x8 f;
          f[0] = (__bf16)v0.x; f[1] = (__bf16)v0.y;
          f[2] = (__bf16)v0.z; f[3] = (__bf16)v0.w;
          f[4] = (__bf16)v1.x; f[5] = (__bf16)v1.y;
          f[6] = (__bf16)v1.z; f[7] = (__bf16)v1.w;
          bfv[kt] = f;
        }
        f32x4 a0 = {0.f,0.f,0.f,0.f}, a1 = {0.f,0.f,0.f,0.f};
        f32x4 a2 = {0.f,0.f,0.f,0.f}, a3 = {0.f,0.f,0.f,0.f};
        #pragma unroll
        for (int kt = 0; kt < 4; ++kt) {
          a0 = __builtin_amdgcn_mfma_f32_16x16x32_bf16(wf[0][0][kt], bfv[kt], a0, 0, 0, 0);
          a1 = __builtin_amdgcn_mfma_f32_16x16x32_bf16(wf[0][1][kt], bfv[kt], a1, 0, 0, 0);
          a2 = __builtin_amdgcn_mfma_f32_16x16x32_bf16(wf[1][0][kt], bfv[kt], a2, 0, 0, 0);
          a3 = __builtin_amdgcn_mfma_f32_16x16x32_bf16(wf[1][1][kt], bfv[kt], a3, 0, 0, 0);
        }
        pacc[et * 4 + 0] = a0;   // (nt0,W)
        pacc[et * 4 + 1] = a1;   // (nt0,A)
        pacc[et * 4 + 2] = a2;   // (nt1,W)
        pacc[et * 4 + 3] = a3;   // (nt1,A)
      }
    }

    // F: finalize(T-G) from this half's named set + plds.
    {
      float sW = plds[0][0][fid] + plds[0][1][fid] + plds[0][2][fid] + plds[0][3][fid];
      float sA = plds[1][0][fid] + plds[1][1][fid] + plds[1][2][fid] + plds[1][3][fid];
      const float a = __expf(sA + ba2s);
      const float t = (sW + bw2s) * a;
      const float dx = x3 - x0, dy = x4 - x1, dz = x5 - x2;
      const float nrm = sqrtf(dx * dx + dy * dy + dz * dz);
      const float inv = t * __builtin_amdgcn_rcpf(fmaxf(nrm, 1e-12f));
      const float m = m_f;
      if (quad == 0 && l16 < 8) {
        float* bp = num4 + (size_t)4 * s_f;
        atomicAdd(bp + 0, dx * inv * m);
        atomicAdd(bp + 1, dy * inv * m);
        atomicAdd(bp + 2, dz * inv * m);
        atomicAdd(bp + 3, a * m);
      }
    }

    // G: drain sd (vmcnt(8) leaves {stg4, at4}); gather x(T+G) into this
    // half's set; rotate the finalize scalars.
    asm volatile("s_waitcnt vmcnt(8)" ::: "memory");
    x0 = x[3 * sNn]; x1 = x[3 * sNn + 1]; x2 = x[3 * sNn + 2];
    x3 = x[3 * dNn]; x4 = x[3 * dNn + 1]; x5 = x[3 * dNn + 2];
    s_f = sNn; m_f = vN ? 1.f : 0.f;

    asm volatile("s_waitcnt lgkmcnt(0)" ::: "memory");
    __builtin_amdgcn_s_barrier();
  };

  int ci = 0;
  for (int it = 0; it < niter; ++it) {
    const int tta = t0 + (2 * it) * G;
    const int ttb = tta + G;
    int ci1 = ci + 1; if (ci1 >= 3) ci1 -= 3;
    int ci2 = ci + 2; if (ci2 >= 3) ci2 -= 3;
    half(tta, ci, ci2, sAf, mAf, xA0, xA1, xA2, xA3, xA4, xA5);
    half(ttb, ci1, ci, sBf, mBf, xB0, xB1, xB2, xB3, xB4, xB5);
    ci = ci2;
  }
}

// ---- Kernel 3: per-node finalize. out = x + num.xyz / num.w (0 if no edges).
__global__ void finalize_kernel(const float* __restrict__ x,
                                const f32x4* __restrict__ num4,
                                float* __restrict__ out, int N) {
  int n = blockIdx.x * blockDim.x + threadIdx.x;
  if (n >= N) return;
  const f32x4 v = num4[n];
  const float inv = (v[3] != 0.f) ? __builtin_amdgcn_rcpf(v[3]) : 0.f;
  out[3 * n + 0] = x[3 * n + 0] + v[0] * inv;
  out[3 * n + 1] = x[3 * n + 1] + v[1] * inv;
  out[3 * n + 2] = x[3 * n + 2] + v[2] * inv;
}

extern "C" void kernel_launch(void* const* d_in, const int* in_sizes, int n_in,
                              void* d_out, int out_size, void* d_ws, size_t ws_size,
                              hipStream_t stream) {
  const float* x    = (const float*)d_in[0];
  const float* m_ij = (const float*)d_in[1];
  const int*   edges = (const int*)d_in[2];
  const float* Ww1 = (const float*)d_in[3];
  const float* bw1 = (const float*)d_in[4];
  const float* Ww2 = (const float*)d_in[5];
  const float* bw2 = (const float*)d_in[6];
  const float* Wa1 = (const float*)d_in[7];
  const float* ba1 = (const float*)d_in[8];
  const float* Wa2 = (const float*)d_in[9];
  const float* ba2 = (const float*)d_in[10];

  const int N = in_sizes[0] / 3;
  const int E = in_sizes[1] / MSG;
  const int* src = edges;        // edges[0] = receiver
  const int* dst = edges + E;    // edges[1] = neighbor

  // Workspace layout (~1.7 MB)
  char* p = (char*)d_ws;
  unsigned short* WtW = (unsigned short*)p; p += (size_t)MSG * MSG * 2;
  unsigned short* WtA = (unsigned short*)p; p += (size_t)MSG * MSG * 2;
  float* num4 = (float*)p; p += (size_t)N * 4 * 4;

  float* out = (float*)d_out;

  const int ntiles = (E + TILE - 1) / TILE;
  const int nb = ntiles < NB_MAX ? ntiles : NB_MAX;

  hipMemsetAsync(num4, 0, (size_t)N * 4 * 4, stream);
  prep_weights_kernel<<<(MSG * MSG + 255) / 256, 256, 0, stream>>>(Ww1, Wa1, WtW, WtA);
  edge_mlp_pipe_kernel<<<nb, TPB, 0, stream>>>(
      m_ij, WtW, WtA, bw1, Ww2, bw2, ba1, Wa2, ba2, src, dst, x, num4, E, ntiles);
  finalize_kernel<<<(N + 255) / 256, 256, 0, stream>>>(x, (const f32x4*)num4, out, N);
}

// Round 12
// 1197.810 us; speedup vs baseline: 2.0262x; 1.0232x over previous
//
#include <hip/hip_runtime.h>
#include <cmath>

#define MSG 128
#define TILE 64      // edges per LDS tile
#define TPB 512      // 8 waves; each wave owns 16 hidden units
#define NB_MAX 512   // 2 blocks/CU

typedef __attribute__((ext_vector_type(8))) __bf16 bf16x8;
typedef __attribute__((ext_vector_type(4))) float f32x4;

__device__ __forceinline__ unsigned short f2bf(float f) {
  union { float f; unsigned u; } v; v.f = f;
  unsigned r = v.u + 0x7FFFu + ((v.u >> 16) & 1u);  // round-to-nearest-even
  return (unsigned short)(r >> 16);
}

// ---- Kernel 1: convert + transpose both hidden-layer weight matrices to bf16.
__global__ void prep_weights_kernel(const float* __restrict__ Ww1,
                                    const float* __restrict__ Wa1,
                                    unsigned short* __restrict__ WtW,
                                    unsigned short* __restrict__ WtA) {
  int idx = blockIdx.x * blockDim.x + threadIdx.x;
  if (idx < MSG * MSG) {
    int k = idx >> 7;
    int n = idx & 127;
    WtW[n * MSG + k] = f2bf(Ww1[idx]);
    WtA[n * MSG + k] = f2bf(Wa1[idx]);
  }
}

__device__ __forceinline__ void gload_lds16(const float* g, float* l) {
  __builtin_amdgcn_global_load_lds(
      (const __attribute__((address_space(1))) void*)g,
      (__attribute__((address_space(3))) void*)l, 16, 0, 0);
}

// ---- Kernel 2: R7 pipeline (best measured) + XCD-PRIVATE accumulators.
// Cross-round finding: delivery rate is ~2.1 TB/s across ALL schedules and
// the scatter cost (~240 us) is ADDITIVE with the MLP stream -> the limiter
// is a shared memory-system resource, dominated by cross-XCD coherence
// ping-pong of device-scope atomics into one 1.6 MB num4 hammered by all
// 256 CUs. Fix: 8 private copies (one per XCD, selected by HW XCC_ID);
// atomics become XCD-local L2 RMWs. Correctness is mapping-independent
// (finalize sums all 8 copies; &7 bounds the index).
__global__ __launch_bounds__(TPB, 2)
void edge_mlp_pipe_kernel(const float* __restrict__ m_ij,
                          const unsigned short* __restrict__ WtW,
                          const unsigned short* __restrict__ WtA,
                          const float* __restrict__ bw1, const float* __restrict__ Ww2,
                          const float* __restrict__ bw2,
                          const float* __restrict__ ba1, const float* __restrict__ Wa2,
                          const float* __restrict__ ba2,
                          const int* __restrict__ src,
                          const int* __restrict__ dst,
                          const float* __restrict__ x,
                          float* __restrict__ numx, int N, int E, int ntiles) {
  __shared__ __align__(16) float buf[2][TILE * MSG];  // 2 x 32KB, swizzled rows
  __shared__ float plds[2][8][TILE];                  // [mlp][wave][edge] 4KB

  const int tid = threadIdx.x;
  const int w = tid >> 6;
  const int lane = tid & 63;
  const int quad = lane >> 4;
  const int l16 = lane & 15;

  // XCD-private accumulator base. XCC_ID (hwreg 20) is uniform per block
  // (a workgroup runs on one CU -> one XCD). Masked &7: any value in 0..7
  // is CORRECT (finalize sums all copies); the right one is merely fastest.
  int xcc;
  asm volatile("s_getreg_b32 %0, hwreg(20, 0, 32)" : "=s"(xcc));
  float* __restrict__ num4 = numx + (size_t)(xcc & 7) * ((size_t)N * 4);

  // --- Persistent weights: wave w owns hidden units [16w, 16w+16).
  // A-frag: A[m = 16w + l16][k = quad*8 + kt*32 + j].
  bf16x8 wf[2][4];     // [mat W/A][kt]
  f32x4 c1[2], c2[2];  // [mat]: layer-1 bias, layer-2 weight @ 16w + quad*4
  {
    const int unit16 = w * 16;
    const size_t ro = (size_t)(unit16 + l16) * MSG + quad * 8;
    #pragma unroll
    for (int kt = 0; kt < 4; ++kt) {
      wf[0][kt] = *(const bf16x8*)(WtW + ro + kt * 32);
      wf[1][kt] = *(const bf16x8*)(WtA + ro + kt * 32);
    }
    const int co = unit16 + quad * 4;
    c1[0] = *(const f32x4*)(bw1 + co);
    c2[0] = *(const f32x4*)(Ww2 + co);
    c1[1] = *(const f32x4*)(ba1 + co);
    c2[1] = *(const f32x4*)(Wa2 + co);
  }
  const float bw2s = bw2[0], ba2s = ba2[0];

  // Stage one 64x128 fp32 tile into buf[bsel]. LDS dest is linear; the XOR
  // swizzle (byte ^= (row&7)<<4, involution, row-preserving) is applied to the
  // GLOBAL source address (T21: both-sides-or-neither).
  auto stage = [&](int tile, int bsel) {
    #pragma unroll
    for (int i = 0; i < 4; ++i) {
      const int chunk = i * TPB + tid;        // 0..2047
      const int db = chunk * 16;              // dest byte in [0, 32768)
      const int row = db >> 9;                // tile row (512B rows)
      const int col = db & 511;
      const int scol = col ^ ((row & 7) << 4);
      int grow = tile * TILE + row;
      if (grow >= E) grow = E - 1;            // clamp (stores guarded later)
      const float* g = m_ij + (size_t)grow * MSG + (scol >> 2);
      gload_lds16(g, &buf[bsel][0] + (db >> 2));
    }
  };

  int tt = blockIdx.x;
  if (tt < ntiles) stage(tt, 0);
  asm volatile("s_waitcnt vmcnt(0)" ::: "memory");
  __builtin_amdgcn_s_barrier();
  int cur = 0;

  for (; tt < ntiles; tt += gridDim.x) {
    // Finalize ownership: waves 0..3, quad==0 lanes own 16 edges each.
    const int eL = w * 16 + l16;
    const int ge = tt * TILE + eL;
    const bool fown = (quad == 0) && (w < 4) && (ge < E);

    // (1) src/dst FIRST (oldest in vmcnt queue: consuming them later will
    //     never force the staging loads below to drain).
    int sN = 0, dN = 0;
    if (fown) { sN = src[ge]; dN = dst[ge]; }

    // (2) fire-and-forget staging of the next tile.
    const int nxt = tt + (int)gridDim.x;
    if (nxt < ntiles) stage(nxt, cur ^ 1);

    // (3) Compute: 4 edge sub-tiles of 16; B[k][n=edge] from swizzled LDS.
    #pragma unroll
    for (int et = 0; et < 4; ++et) {
      const int row = et * 16 + l16;
      const int rbase = row * MSG;            // float index
      const int xorf = (row & 7) << 2;        // float-index xor (= byte<<4)
      bf16x8 bf[4];
      #pragma unroll
      for (int kt = 0; kt < 4; ++kt) {
        const int c0 = quad * 8 + kt * 32;
        const f32x4 v0 = *(const f32x4*)(&buf[cur][rbase + (c0 ^ xorf)]);
        const f32x4 v1 = *(const f32x4*)(&buf[cur][rbase + ((c0 + 4) ^ xorf)]);
        bf16x8 f;
        f[0] = (__bf16)v0.x; f[1] = (__bf16)v0.y;
        f[2] = (__bf16)v0.z; f[3] = (__bf16)v0.w;
        f[4] = (__bf16)v1.x; f[5] = (__bf16)v1.y;
        f[6] = (__bf16)v1.z; f[7] = (__bf16)v1.w;
        bf[kt] = f;
      }
      f32x4 accW = {0.f, 0.f, 0.f, 0.f};
      f32x4 accA = {0.f, 0.f, 0.f, 0.f};
      #pragma unroll
      for (int kt = 0; kt < 4; ++kt) {
        accW = __builtin_amdgcn_mfma_f32_16x16x32_bf16(wf[0][kt], bf[kt], accW, 0, 0, 0);
        accA = __builtin_amdgcn_mfma_f32_16x16x32_bf16(wf[1][kt], bf[kt], accA, 0, 0, 0);
      }
      // Fused epilogue over this wave's 4 units/lane: silu(h)*W2 partials.
      float pW = 0.f, pA = 0.f;
      #pragma unroll
      for (int r = 0; r < 4; ++r) {
        const float hw = accW[r] + c1[0][r];
        const float ha = accA[r] + c1[1][r];
        // silu via rcp: saturation-safe (exp(-h)->inf => rcp->0 => silu->0).
        pW += (hw * c2[0][r]) * __builtin_amdgcn_rcpf(1.f + __expf(-hw));
        pA += (ha * c2[1][r]) * __builtin_amdgcn_rcpf(1.f + __expf(-ha));
      }
      pW += __shfl_xor(pW, 16, 64); pW += __shfl_xor(pW, 32, 64);
      pA += __shfl_xor(pA, 16, 64); pA += __shfl_xor(pA, 32, 64);
      if (quad == 0) {
        plds[0][w][et * 16 + l16] = pW;
        plds[1][w][et * 16 + l16] = pA;
      }
    }

    // Barrier A: partials visible to all waves.
    asm volatile("s_waitcnt lgkmcnt(0)" ::: "memory");
    __builtin_amdgcn_s_barrier();

    // (4) Finalize AFTER compute: the wait for sN/dN + x gathers lands here;
    //     atomics go to this block's XCD-private copy (no cross-die
    //     coherence ping-pong).
    if (fown) {
      const float sx = x[3 * sN], sy = x[3 * sN + 1], sz = x[3 * sN + 2];
      const float gx = x[3 * dN], gy = x[3 * dN + 1], gz = x[3 * dN + 2];
      float sW = 0.f, sA = 0.f;
      #pragma unroll
      for (int ww = 0; ww < 8; ++ww) {
        sW += plds[0][ww][eL];
        sA += plds[1][ww][eL];
      }
      const float a = __expf(sA + ba2s);
      const float t = (sW + bw2s) * a;  // w*a; /a_i deferred to finalize kernel
      const float dx = gx - sx, dy = gy - sy, dz = gz - sz;
      const float nrm = sqrtf(dx * dx + dy * dy + dz * dz);
      const float inv = t * __builtin_amdgcn_rcpf(fmaxf(nrm, 1e-12f));
      float* basep = num4 + (size_t)4 * sN;
      atomicAdd(basep + 0, dx * inv);
      atomicAdd(basep + 1, dy * inv);
      atomicAdd(basep + 2, dz * inv);
      atomicAdd(basep + 3, a);
    }

    // Barrier B: next tile's staging must be in LDS for ALL waves.
    // Wave-uniform split (w is uniform): waves 0..3 leave only their 4
    // atomics outstanding; waves 4..7 drain their staging fully.
    if (w < 4) {
      asm volatile("s_waitcnt vmcnt(4) lgkmcnt(0)" ::: "memory");
    } else {
      asm volatile("s_waitcnt vmcnt(0) lgkmcnt(0)" ::: "memory");
    }
    __builtin_amdgcn_s_barrier();
    cur ^= 1;
  }
}

// ---- Kernel 3: per-node finalize. Sum the 8 XCD-private copies, then
// out = x + num.xyz / num.w (0 if no edges).
__global__ void finalize_kernel(const float* __restrict__ x,
                                const float* __restrict__ numx,
                                float* __restrict__ out, int N) {
  int n = blockIdx.x * blockDim.x + threadIdx.x;
  if (n >= N) return;
  f32x4 v = {0.f, 0.f, 0.f, 0.f};
  #pragma unroll
  for (int c = 0; c < 8; ++c) {
    const f32x4 u = *(const f32x4*)(numx + ((size_t)c * N + n) * 4);
    v[0] += u[0]; v[1] += u[1]; v[2] += u[2]; v[3] += u[3];
  }
  const float inv = (v[3] != 0.f) ? __builtin_amdgcn_rcpf(v[3]) : 0.f;
  out[3 * n + 0] = x[3 * n + 0] + v[0] * inv;
  out[3 * n + 1] = x[3 * n + 1] + v[1] * inv;
  out[3 * n + 2] = x[3 * n + 2] + v[2] * inv;
}

extern "C" void kernel_launch(void* const* d_in, const int* in_sizes, int n_in,
                              void* d_out, int out_size, void* d_ws, size_t ws_size,
                              hipStream_t stream) {
  const float* x    = (const float*)d_in[0];
  const float* m_ij = (const float*)d_in[1];
  const int*   edges = (const int*)d_in[2];
  const float* Ww1 = (const float*)d_in[3];
  const float* bw1 = (const float*)d_in[4];
  const float* Ww2 = (const float*)d_in[5];
  const float* bw2 = (const float*)d_in[6];
  const float* Wa1 = (const float*)d_in[7];
  const float* ba1 = (const float*)d_in[8];
  const float* Wa2 = (const float*)d_in[9];
  const float* ba2 = (const float*)d_in[10];

  const int N = in_sizes[0] / 3;
  const int E = in_sizes[1] / MSG;
  const int* src = edges;        // edges[0] = receiver
  const int* dst = edges + E;    // edges[1] = neighbor

  // Workspace layout (~12.9 MB: 8 XCD-private num4 copies + weights)
  char* p = (char*)d_ws;
  unsigned short* WtW = (unsigned short*)p; p += (size_t)MSG * MSG * 2;
  unsigned short* WtA = (unsigned short*)p; p += (size_t)MSG * MSG * 2;
  float* numx = (float*)p; p += (size_t)8 * N * 4 * 4;

  float* out = (float*)d_out;

  const int ntiles = (E + TILE - 1) / TILE;
  const int nb = ntiles < NB_MAX ? ntiles : NB_MAX;

  hipMemsetAsync(numx, 0, (size_t)8 * N * 4 * 4, stream);
  prep_weights_kernel<<<(MSG * MSG + 255) / 256, 256, 0, stream>>>(Ww1, Wa1, WtW, WtA);
  edge_mlp_pipe_kernel<<<nb, TPB, 0, stream>>>(
      m_ij, WtW, WtA, bw1, Ww2, bw2, ba1, Wa2, ba2, src, dst, x, numx, N, E, ntiles);
  finalize_kernel<<<(N + 255) / 256, 256, 0, stream>>>(x, numx, out, N);
}